// Round 15
// baseline (552.877 us; speedup 1.0000x reference)
//
#include <hip/hip_runtime.h>
#include <hip/hip_bf16.h>

// ---------------- problem constants (match reference) ----------------
static constexpr int N_NODES = 100000;
static constexpr int N_EDGES = 3200000;
static constexpr int NFEAT   = 512;
static constexpr int NHID    = 256;
static constexpr int NCLASS  = 64;

static constexpr int SCAN_CHUNK = 2048;                       // 256 thr * 8 items
static constexpr int NB = (N_NODES + SCAN_CHUNK - 1) / SCAN_CHUNK; // 49

static constexpr int PARTS = 8;
static constexpr int NODES_PER_PART = N_NODES / PARTS;         // 12500
static constexpr int EDGES_PER_BLOCK = 1024;                   // 256 thr * 4 (hist)
static constexpr int NCHUNK = N_EDGES / EDGES_PER_BLOCK;       // 3125

// fused gemm1||scatter geometry (512-thread blocks)
static constexpr int NG_GEMM1 = (N_NODES + 127) / 128;                     // 782
static constexpr int EDGES_PER_BLOCK2 = 2048;                              // 512 thr * 4
static constexpr int NCHUNK2 = (N_EDGES + EDGES_PER_BLOCK2 - 1) / EDGES_PER_BLOCK2; // 1563
static constexpr int NS_SCAT = NCHUNK2 * PARTS;                            // 12504

using short8 = __attribute__((ext_vector_type(8))) short;
using f32x4  = __attribute__((ext_vector_type(4))) float;
using fv4    = __attribute__((ext_vector_type(4))) float;
using fv2    = __attribute__((ext_vector_type(2))) float;
using iv4    = __attribute__((ext_vector_type(4))) int;
using fvec4  = __attribute__((ext_vector_type(4))) float;

__device__ __forceinline__ short f2bf_bits(float f) {
    __hip_bfloat16 h = __float2bfloat16(f);
    return *reinterpret_cast<short*>(&h);
}

// fp8 (OCP e4m3) helpers — gfx950 v_cvt_pk_* instructions
__device__ __forceinline__ unsigned char f2fp8(float v) {
    int p = __builtin_amdgcn_cvt_pk_fp8_f32(v, v, 0, false);
    return (unsigned char)(p & 0xff);
}

// acc2[0..3] += w * fp8[0..7] (packed fv2 -> v_pk_fma_f32)
__device__ __forceinline__ void fp8x8_acc_pk(int vx, int vy, float w, fv2* acc2) {
    fv2 w2; w2[0] = w; w2[1] = w;
    acc2[0] += w2 * __builtin_amdgcn_cvt_pk_f32_fp8(vx, false);
    acc2[1] += w2 * __builtin_amdgcn_cvt_pk_f32_fp8(vx, true);
    acc2[2] += w2 * __builtin_amdgcn_cvt_pk_f32_fp8(vy, false);
    acc2[3] += w2 * __builtin_amdgcn_cvt_pk_f32_fp8(vy, true);
}

// acc2[0..7] += w * fp8[0..15] (16 cols from one 16B gather)
__device__ __forceinline__ void fp8x16_acc_pk(iv4 v, float w, fv2* acc2) {
    fp8x8_acc_pk(v.x, v.y, w, acc2);
    fp8x8_acc_pk(v.z, v.w, w, acc2 + 4);
}

#define GLOBAL_TO_LDS(gsrc, ldst)                                                        \
    __builtin_amdgcn_global_load_lds((const __attribute__((address_space(1))) void*)(gsrc), \
                                     (__attribute__((address_space(3))) void*)(ldst), 16, 0, 0)

// ---------------- CSR build ----------------
__global__ __launch_bounds__(256) void hist_kernel(const int* __restrict__ edst,
                                                   int* __restrict__ counts) {
    int e0 = blockIdx.x * EDGES_PER_BLOCK + threadIdx.x * 4;
    iv4 d4 = __builtin_nontemporal_load((const iv4*)(edst + e0));
    atomicAdd(&counts[d4.x], 1);
    atomicAdd(&counts[d4.y], 1);
    atomicAdd(&counts[d4.z], 1);
    atomicAdd(&counts[d4.w], 1);
}

__global__ __launch_bounds__(256) void scan_part_kernel(const int* __restrict__ counts,
                                                        int* __restrict__ partials) {
    int b = blockIdx.x, t = threadIdx.x;
    int base = b * SCAN_CHUNK + t * 8;
    int s = 0;
#pragma unroll
    for (int j = 0; j < 8; ++j) {
        int i = base + j;
        if (i < N_NODES) s += counts[i];
    }
    __shared__ int sd[256];
    sd[t] = s;
    __syncthreads();
    for (int off = 128; off > 0; off >>= 1) {
        if (t < off) sd[t] += sd[t + off];
        __syncthreads();
    }
    if (t == 0) partials[b] = sd[0];
}

__global__ void scan_mid_kernel(int* __restrict__ partials) {
    if (threadIdx.x == 0) {
        int run = 0;
        for (int i = 0; i < NB; ++i) {
            int v = partials[i];
            partials[i] = run;
            run += v;
        }
    }
}

__global__ __launch_bounds__(256) void scan_final_kernel(int* __restrict__ counts_cursor,
                                                         int* __restrict__ row_ptr,
                                                         const int* __restrict__ partials) {
    int b = blockIdx.x, t = threadIdx.x;
    int base = b * SCAN_CHUNK + t * 8;
    int v[8];
    int tsum = 0;
#pragma unroll
    for (int j = 0; j < 8; ++j) {
        int i = base + j;
        v[j] = (i < N_NODES) ? counts_cursor[i] : 0;
        tsum += v[j];
    }
    __shared__ int sd[256];
    sd[t] = tsum;
    __syncthreads();
    for (int off = 1; off < 256; off <<= 1) {
        int x = (t >= off) ? sd[t - off] : 0;
        __syncthreads();
        sd[t] += x;
        __syncthreads();
    }
    int run = sd[t] - tsum + partials[b];
#pragma unroll
    for (int j = 0; j < 8; ++j) {
        int i = base + j;
        if (i < N_NODES) {
            row_ptr[i] = run;
            counts_cursor[i] = run;
        }
        run += v[j];
    }
    if (b == 0 && t == 0) row_ptr[N_NODES] = N_EDGES;
}

// ---------------- small transpose+cast: W[K][N] f32 -> WT[N][K] bf16 ----------------
__global__ __launch_bounds__(256) void transpose_w_kernel(const float* __restrict__ W,
                                                          __hip_bfloat16* __restrict__ WT,
                                                          int K, int N) {
    int idx = blockIdx.x * 256 + threadIdx.x;
    if (idx < K * N) {
        int k = idx / N, n = idx % N;
        WT[(size_t)n * K + k] = __float2bfloat16(W[idx]);
    }
}

// ---------------- FUSED: gemm1 (MFMA-bound) || scatter (latency/RMW-bound) ----------
// r15: scatter sits at the 8B-store line-RMW floor (r11-r13: WRITE ~165-220 MB, VALU
// 4%, HBM 27%) while gemm1 is compute-bound — both independent, previously serialized.
// One kernel, interleaved blockIdx: each CU co-hosts a gemm block (8 waves, 64KB LDS)
// and a scatter block -> gemm MFMA fills scatter's stall cycles. Target ~max not sum.
__global__ __launch_bounds__(512) void fused_gemm1_scatter(
        const float* __restrict__ A, const __hip_bfloat16* __restrict__ BT,
        unsigned char* __restrict__ C8, int M,
        const int* __restrict__ esrc, const int* __restrict__ edst,
        const float* __restrict__ ew, int* __restrict__ cursor,
        int2* __restrict__ pk) {
    int bid = blockIdx.x;
    bool isGemm;
    int idx;
    if (bid < 2 * NG_GEMM1) {       // interleave gemm/scatter over the first 2*NG blocks
        isGemm = !(bid & 1);
        idx = bid >> 1;
    } else {
        isGemm = false;
        idx = bid - NG_GEMM1;
    }

    if (isGemm) {
        // ---- gemm1 body (identical to r14's 8-wave 128x256 kernel) ----
        constexpr int K = NFEAT;   // 512
        constexpr int N = NHID;    // 256
        constexpr int BM = 128, BK = 32;
        constexpr int NSTEP = K / BK;  // 16
        __shared__ __align__(16) float          As[2][BM * BK];  // 2 x 16 KB
        __shared__ __align__(16) __hip_bfloat16 Bs[2][256 * BK]; // 2 x 16 KB
        const int tid = threadIdx.x;
        const int lane = tid & 63, wave = tid >> 6;   // 8 waves
        const int wr = wave >> 2, wc = wave & 3;      // 2 x 4 wave grid
        const int laneRow = lane & 15, laneK = lane >> 4;
        const int row0 = idx * BM;

        f32x4 acc[4][4] = {};

        auto STAGE = [&](int step) {
            {
                float* dst = As[step & 1];
#pragma unroll
                for (int it = 0; it < 2; ++it) {
                    int q = wave * 2 + it;            // 16 chunks of 1KB
                    int r = q * 8 + (lane >> 3);
                    int c16 = lane & 7;
                    int src_c = (c16 ^ ((r & 3) << 1)) * 4;  // floats
                    int rg = row0 + r; rg = (rg < M) ? rg : (M - 1);
                    const float* src = A + (size_t)rg * K + step * BK + src_c;
                    GLOBAL_TO_LDS(src, dst + q * 256 + lane * 4);
                }
            }
            {
                __hip_bfloat16* dst = Bs[step & 1];
#pragma unroll
                for (int it = 0; it < 2; ++it) {
                    int idx2 = tid + it * 512;        // 1024 granules of 16B
                    int n = idx2 >> 2;
                    int gk = (idx2 & 3) ^ ((n >> 1) & 3);
                    const __hip_bfloat16* src = BT + (size_t)n * K + step * BK + gk * 8;
                    GLOBAL_TO_LDS(src, dst + (size_t)idx2 * 8);
                }
            }
        };

        STAGE(0);

#pragma unroll
        for (int t = 0; t < NSTEP; ++t) {
            __syncthreads();
            if (t + 1 < NSTEP) STAGE(t + 1);
            short8 af[4];
#pragma unroll
            for (int i = 0; i < 4; ++i) {
                int rr = wr * 64 + i * 16 + laneRow;
                int ck = laneK ^ (rr & 3);
                const float* ap = As[t & 1] + rr * BK + ck * 8;
                fv4 a0 = *(const fv4*)ap;
                fv4 a1 = *(const fv4*)(ap + 4);
                short8 v;
#pragma unroll
                for (int j = 0; j < 4; ++j) v[j] = f2bf_bits(a0[j]);
#pragma unroll
                for (int j = 0; j < 4; ++j) v[4 + j] = f2bf_bits(a1[j]);
                af[i] = v;
            }
            short8 bfr[4];
#pragma unroll
            for (int j = 0; j < 4; ++j) {
                int n = wc * 64 + j * 16 + laneRow;
                int pg = laneK ^ ((n >> 1) & 3);
                bfr[j] = *(const short8*)(Bs[t & 1] + n * BK + pg * 8);
            }
#pragma unroll
            for (int i = 0; i < 4; ++i)
#pragma unroll
                for (int j = 0; j < 4; ++j)
                    acc[i][j] = __builtin_amdgcn_mfma_f32_16x16x32_bf16(af[i], bfr[j], acc[i][j], 0, 0, 0);
        }
#pragma unroll
        for (int i = 0; i < 4; ++i) {
            int rbase = row0 + wr * 64 + i * 16 + laneK * 4;
#pragma unroll
            for (int j = 0; j < 4; ++j) {
                int col = wc * 64 + j * 16 + laneRow;
#pragma unroll
                for (int q = 0; q < 4; ++q) {
                    int row = rbase + q;
                    if (row < M) C8[(size_t)row * N + col] = f2fp8(acc[i][j][q]);
                }
            }
        }
    } else {
        // ---- scatter body (512 threads, 2048 edges/block, partition = idx&7) ----
        int p = idx & (PARTS - 1);
        int chunk = idx >> 3;
        int e0 = chunk * EDGES_PER_BLOCK2 + threadIdx.x * 4;
        if (e0 < N_EDGES) {
            int lo = p * NODES_PER_PART, hi = lo + NODES_PER_PART;
            iv4   d4 = __builtin_nontemporal_load((const iv4*)(edst + e0));
            iv4   s4 = __builtin_nontemporal_load((const iv4*)(esrc + e0));
            fvec4 w4 = __builtin_nontemporal_load((const fvec4*)(ew + e0));
            int   dd[4] = {d4.x, d4.y, d4.z, d4.w};
            int   ss[4] = {s4.x, s4.y, s4.z, s4.w};
            float ww[4] = {w4.x, w4.y, w4.z, w4.w};
#pragma unroll
            for (int k = 0; k < 4; ++k) {
                if (dd[k] >= lo && dd[k] < hi) {
                    int pos = atomicAdd(&cursor[dd[k]], 1);
                    pk[pos] = make_int2(ss[k], __float_as_int(ww[k]));
                }
            }
        }
    }
}

// ---------------- GEMM2: support1[M,64](fp8) = H0[M,256](bf16) @ W2T[64,256]^T ------
__global__ __launch_bounds__(256) void gemm2_mfma(const __hip_bfloat16* __restrict__ A,
                                                  const __hip_bfloat16* __restrict__ BT,
                                                  unsigned char* __restrict__ C8,
                                                  int M) {
    constexpr int K = NHID;    // 256
    constexpr int N = NCLASS;  // 64
    constexpr int BM = 128;
    __shared__ __align__(16) __hip_bfloat16 Bs[N * K];  // 32 KB
    const int tid = threadIdx.x;
    const int lane = tid & 63, wave = tid >> 6;
    const int wr = wave >> 1, wc = wave & 1;
    const int laneRow = lane & 15, laneK = lane >> 4;
    const int row0 = blockIdx.x * BM;

#pragma unroll
    for (int it = 0; it < 8; ++it) {
        int idx = tid + it * 256;
        int n = idx >> 5;
        int kk = (idx & 31) ^ (n & 7);
        const __hip_bfloat16* src = BT + (size_t)n * K + kk * 8;
        GLOBAL_TO_LDS(src, Bs + (size_t)idx * 8);
    }

    int arow[4];
#pragma unroll
    for (int i = 0; i < 4; ++i) {
        int r = row0 + wr * 64 + i * 16 + laneRow;
        arow[i] = (r < M) ? r : (M - 1);
    }

    f32x4 acc[4][2] = {};
    __syncthreads();

#pragma unroll
    for (int k0 = 0; k0 < K; k0 += 32) {
        short8 af[4];
#pragma unroll
        for (int i = 0; i < 4; ++i)
            af[i] = *(const short8*)(A + (size_t)arow[i] * K + k0 + laneK * 8);
        short8 bfr[2];
#pragma unroll
        for (int j = 0; j < 2; ++j) {
            int n = wc * 32 + j * 16 + laneRow;
            int kkw = (k0 >> 3) + laneK;
            int pkk = kkw ^ (n & 7);
            bfr[j] = *(const short8*)(Bs + (size_t)n * 32 * 8 + pkk * 8);
        }
#pragma unroll
        for (int i = 0; i < 4; ++i)
#pragma unroll
            for (int j = 0; j < 2; ++j)
                acc[i][j] = __builtin_amdgcn_mfma_f32_16x16x32_bf16(af[i], bfr[j], acc[i][j], 0, 0, 0);
    }

#pragma unroll
    for (int i = 0; i < 4; ++i) {
        int rbase = row0 + wr * 64 + i * 16 + laneK * 4;
#pragma unroll
        for (int j = 0; j < 2; ++j) {
            int col = wc * 32 + j * 16 + laneRow;
#pragma unroll
            for (int q = 0; q < 4; ++q) {
                int row = rbase + q;
                if (row < M) C8[(size_t)row * N + col] = f2fp8(acc[i][j][q]);
            }
        }
    }
}

// ---------------- SPMM layer1: one wave = one node = FULL 256-col row.
// Lanes = 4 edge slots (lane>>4) x 16 chunks of 16 cols (16B gather per lane).
// x2 unroll -> 8 edges in flight per wave; packed fv2 accumulate (v_pk_fma_f32).
__global__ __launch_bounds__(256) void spmm1_kernel(const unsigned char* __restrict__ s0_8,
                                                    const int* __restrict__ row_ptr,
                                                    const int2* __restrict__ pk,
                                                    const float* __restrict__ b1,
                                                    __hip_bfloat16* __restrict__ H0) {
    int node = blockIdx.x * 4 + (threadIdx.x >> 6);
    int lane = threadIdx.x & 63;
    int j = lane >> 4;                 // edge slot 0..3
    int c = lane & 15;                 // column chunk (16 cols each) -> 256 cols
    int coff = c * 16;
    int beg = row_ptr[node], end = row_ptr[node + 1];
    fv2 acc2[8] = {};
    for (int base = beg; base + j < end; base += 8) {
        int2 pe0 = pk[base + j];
        int i1 = base + 4 + j;
        int2 pe1 = (i1 < end) ? pk[i1] : make_int2(0, 0);
        float w0 = __int_as_float(pe0.y);
        float w1 = __int_as_float(pe1.y);
        iv4 v0 = *(const iv4*)(s0_8 + (size_t)pe0.x * NHID + coff);
        iv4 v1 = *(const iv4*)(s0_8 + (size_t)pe1.x * NHID + coff);
        fp8x16_acc_pk(v0, w0, acc2);
        fp8x16_acc_pk(v1, w1, acc2);
    }
    float accf[16];
#pragma unroll
    for (int k = 0; k < 8; ++k) { accf[2 * k] = acc2[k][0]; accf[2 * k + 1] = acc2[k][1]; }
#pragma unroll
    for (int m = 16; m < 64; m <<= 1)
#pragma unroll
        for (int k = 0; k < 16; ++k) accf[k] += __shfl_xor(accf[k], m);
    if (lane < 16) {
        short8 o0, o1;
#pragma unroll
        for (int k = 0; k < 8; ++k)  o0[k] = f2bf_bits(fmaxf(accf[k] + b1[coff + k], 0.f));
#pragma unroll
        for (int k = 0; k < 8; ++k)  o1[k] = f2bf_bits(fmaxf(accf[8 + k] + b1[coff + 8 + k], 0.f));
        __hip_bfloat16* dst = H0 + (size_t)node * NHID + coff;
        *(short8*)dst = o0;
        *(short8*)(dst + 8) = o1;
    }
}

// ---------------- SPMM layer2 + bias + log_softmax (fp8 gather, 8x8, x2 unroll,
// packed fv2 accumulate) ---------------------------------------------------------------
__global__ __launch_bounds__(256) void spmm2_softmax_kernel(const unsigned char* __restrict__ s1_8,
                                                            const int* __restrict__ row_ptr,
                                                            const int2* __restrict__ pk,
                                                            const float* __restrict__ b2,
                                                            float* __restrict__ out) {
    int node = blockIdx.x * 4 + (threadIdx.x >> 6);
    int lane = threadIdx.x & 63;
    int j = lane >> 3;   // edge slot 0..7
    int c = lane & 7;    // class chunk (8 classes each)
    int beg = row_ptr[node], end = row_ptr[node + 1];
    fv2 acc2[4] = {};
    for (int base = beg; base + j < end; base += 16) {
        int2 pe0 = pk[base + j];
        int i1 = base + 8 + j;
        int2 pe1 = (i1 < end) ? pk[i1] : make_int2(0, 0);
        float w0 = __int_as_float(pe0.y);
        float w1 = __int_as_float(pe1.y);
        int2 v0 = *(const int2*)(s1_8 + (size_t)pe0.x * NCLASS + c * 8);
        int2 v1 = *(const int2*)(s1_8 + (size_t)pe1.x * NCLASS + c * 8);
        fp8x8_acc_pk(v0.x, v0.y, w0, acc2);
        fp8x8_acc_pk(v1.x, v1.y, w1, acc2);
    }
    float acc[8];
#pragma unroll
    for (int k = 0; k < 4; ++k) { acc[2 * k] = acc2[k][0]; acc[2 * k + 1] = acc2[k][1]; }
#pragma unroll
    for (int m = 8; m < 64; m <<= 1)
#pragma unroll
        for (int k = 0; k < 8; ++k) acc[k] += __shfl_xor(acc[k], m);

    fv4 blo = *(const fv4*)(b2 + c * 8);
    fv4 bhi = *(const fv4*)(b2 + c * 8 + 4);
    float z[8];
#pragma unroll
    for (int k = 0; k < 4; ++k) z[k] = acc[k] + blo[k];
#pragma unroll
    for (int k = 0; k < 4; ++k) z[4 + k] = acc[4 + k] + bhi[k];

    float mx = z[0];
#pragma unroll
    for (int k = 1; k < 8; ++k) mx = fmaxf(mx, z[k]);
#pragma unroll
    for (int m = 1; m < 8; m <<= 1) mx = fmaxf(mx, __shfl_xor(mx, m));
    float s = 0.f;
#pragma unroll
    for (int k = 0; k < 8; ++k) s += __expf(z[k] - mx);
#pragma unroll
    for (int m = 1; m < 8; m <<= 1) s += __shfl_xor(s, m);
    float lg = __logf(s);
    if (lane < 8) {
        f32x4 o0, o1;
#pragma unroll
        for (int k = 0; k < 4; ++k) o0[k] = z[k] - mx - lg;
#pragma unroll
        for (int k = 0; k < 4; ++k) o1[k] = z[4 + k] - mx - lg;
        float* dst = out + (size_t)node * NCLASS + c * 8;
        *(f32x4*)dst = o0;
        *(f32x4*)(dst + 4) = o1;
    }
}

// ---------------- host launch ----------------
extern "C" void kernel_launch(void* const* d_in, const int* in_sizes, int n_in,
                              void* d_out, int out_size, void* d_ws, size_t ws_size,
                              hipStream_t stream) {
    const float* x    = (const float*)d_in[0];
    const int*   esrc = (const int*)d_in[1];
    const int*   edst = (const int*)d_in[2];
    const float* ew   = (const float*)d_in[3];
    const float* W1   = (const float*)d_in[4];
    const float* b1   = (const float*)d_in[5];
    const float* W2   = (const float*)d_in[6];
    const float* b2   = (const float*)d_in[7];
    float* out = (float*)d_out;

    char* ws = (char*)d_ws;
    size_t off = 0;
    auto alloc = [&](size_t bytes) {
        size_t o = off;
        off = (off + bytes + 255) & ~(size_t)255;
        return o;
    };
    unsigned char* support0 = (unsigned char*)(ws + alloc((size_t)N_NODES * NHID));
    __hip_bfloat16* H0      = (__hip_bfloat16*)(ws + alloc((size_t)N_NODES * NHID * 2));
    unsigned char* support1 = (unsigned char*)(ws + alloc((size_t)N_NODES * NCLASS));
    int2*  pk         = (int2*)(ws + alloc((size_t)N_EDGES * 8));
    int*   row_ptr    = (int*)(ws + alloc((size_t)(N_NODES + 1) * 4));
    int*   cursor     = (int*)(ws + alloc((size_t)N_NODES * 4));
    int*   partials   = (int*)(ws + alloc(256 * 4));
    __hip_bfloat16* W1T = (__hip_bfloat16*)(ws + alloc((size_t)NHID * NFEAT * 2));
    __hip_bfloat16* W2T = (__hip_bfloat16*)(ws + alloc((size_t)NCLASS * NHID * 2));

    // --- weight transposes (bf16) ---
    transpose_w_kernel<<<(NFEAT * NHID + 255) / 256, 256, 0, stream>>>(W1, W1T, NFEAT, NHID);
    transpose_w_kernel<<<(NHID * NCLASS + 255) / 256, 256, 0, stream>>>(W2, W2T, NHID, NCLASS);

    // --- CSR build prefix: hist -> scan (row_ptr + cursors ready for scatter) ---
    hipMemsetAsync(cursor, 0, (size_t)N_NODES * 4, stream);
    hist_kernel<<<NCHUNK, 256, 0, stream>>>(edst, cursor);
    scan_part_kernel<<<NB, 256, 0, stream>>>(cursor, partials);
    scan_mid_kernel<<<1, 64, 0, stream>>>(partials);
    scan_final_kernel<<<NB, 256, 0, stream>>>(cursor, row_ptr, partials);

    // --- FUSED gemm1 || scatter (independent work co-scheduled) ---
    fused_gemm1_scatter<<<2 * NG_GEMM1 + (NS_SCAT - NG_GEMM1), 512, 0, stream>>>(
        x, W1T, support0, N_NODES, esrc, edst, ew, cursor, pk);

    // --- Layer 1 aggregate ---
    spmm1_kernel<<<N_NODES / 4, 256, 0, stream>>>(support0, row_ptr, pk, b1, H0);

    // --- Layer 2 ---
    gemm2_mfma<<<(N_NODES + 127) / 128, 256, 0, stream>>>(H0, W2T, support1, N_NODES);
    spmm2_softmax_kernel<<<N_NODES / 4, 256, 0, stream>>>(support1, row_ptr, pk, b2, out);
}

// Round 16
// 509.968 us; speedup vs baseline: 1.0841x; 1.0841x over previous
//
#include <hip/hip_runtime.h>
#include <hip/hip_bf16.h>

// ---------------- problem constants (match reference) ----------------
static constexpr int N_NODES = 100000;
static constexpr int N_EDGES = 3200000;
static constexpr int NFEAT   = 512;
static constexpr int NHID    = 256;
static constexpr int NCLASS  = 64;

static constexpr int SCAN_CHUNK = 2048;                       // 256 thr * 8 items
static constexpr int NB = (N_NODES + SCAN_CHUNK - 1) / SCAN_CHUNK; // 49

static constexpr int EDGES_PER_BLOCK = 1024;                   // 256 thr * 4 (hist)
static constexpr int NCHUNK = N_EDGES / EDGES_PER_BLOCK;       // 3125

// r16 bucket scatter: 256 nodes per bucket; one pass-B block OWNS one bucket's
// pk region (64KB avg) -> every pk line written by one resident block -> L2
// merges -> writeback once (kills the 8B-store line-RMW floor seen r4-r13).
static constexpr int BK2_SHIFT = 8;
static constexpr int NBUCK2 = (N_NODES + 255) >> 8;            // 391
static constexpr int BIN_EPB = 8192;                           // 1024 thr * 8
static constexpr int NBIN = (N_EDGES + BIN_EPB - 1) / BIN_EPB; // 391

using short8 = __attribute__((ext_vector_type(8))) short;
using f32x4  = __attribute__((ext_vector_type(4))) float;
using fv4    = __attribute__((ext_vector_type(4))) float;
using fv2    = __attribute__((ext_vector_type(2))) float;
using iv4    = __attribute__((ext_vector_type(4))) int;
using iv2    = __attribute__((ext_vector_type(2))) int;
using fvec4  = __attribute__((ext_vector_type(4))) float;

__device__ __forceinline__ short f2bf_bits(float f) {
    __hip_bfloat16 h = __float2bfloat16(f);
    return *reinterpret_cast<short*>(&h);
}

// fp8 (OCP e4m3) helpers — gfx950 v_cvt_pk_* instructions
__device__ __forceinline__ unsigned char f2fp8(float v) {
    int p = __builtin_amdgcn_cvt_pk_fp8_f32(v, v, 0, false);
    return (unsigned char)(p & 0xff);
}

// acc2[0..3] += w * fp8[0..7] (packed fv2 -> v_pk_fma_f32)
__device__ __forceinline__ void fp8x8_acc_pk(int vx, int vy, float w, fv2* acc2) {
    fv2 w2; w2[0] = w; w2[1] = w;
    acc2[0] += w2 * __builtin_amdgcn_cvt_pk_f32_fp8(vx, false);
    acc2[1] += w2 * __builtin_amdgcn_cvt_pk_f32_fp8(vx, true);
    acc2[2] += w2 * __builtin_amdgcn_cvt_pk_f32_fp8(vy, false);
    acc2[3] += w2 * __builtin_amdgcn_cvt_pk_f32_fp8(vy, true);
}

// acc2[0..7] += w * fp8[0..15] (16 cols from one 16B gather)
__device__ __forceinline__ void fp8x16_acc_pk(iv4 v, float w, fv2* acc2) {
    fp8x8_acc_pk(v.x, v.y, w, acc2);
    fp8x8_acc_pk(v.z, v.w, w, acc2 + 4);
}

#define GLOBAL_TO_LDS(gsrc, ldst)                                                        \
    __builtin_amdgcn_global_load_lds((const __attribute__((address_space(1))) void*)(gsrc), \
                                     (__attribute__((address_space(3))) void*)(ldst), 16, 0, 0)

// ---------------- CSR build ----------------
__global__ __launch_bounds__(256) void hist_kernel(const int* __restrict__ edst,
                                                   int* __restrict__ counts) {
    int e0 = blockIdx.x * EDGES_PER_BLOCK + threadIdx.x * 4;
    iv4 d4 = __builtin_nontemporal_load((const iv4*)(edst + e0));
    atomicAdd(&counts[d4.x], 1);
    atomicAdd(&counts[d4.y], 1);
    atomicAdd(&counts[d4.z], 1);
    atomicAdd(&counts[d4.w], 1);
}

__global__ __launch_bounds__(256) void scan_part_kernel(const int* __restrict__ counts,
                                                        int* __restrict__ partials) {
    int b = blockIdx.x, t = threadIdx.x;
    int base = b * SCAN_CHUNK + t * 8;
    int s = 0;
#pragma unroll
    for (int j = 0; j < 8; ++j) {
        int i = base + j;
        if (i < N_NODES) s += counts[i];
    }
    __shared__ int sd[256];
    sd[t] = s;
    __syncthreads();
    for (int off = 128; off > 0; off >>= 1) {
        if (t < off) sd[t] += sd[t + off];
        __syncthreads();
    }
    if (t == 0) partials[b] = sd[0];
}

__global__ void scan_mid_kernel(int* __restrict__ partials) {
    if (threadIdx.x == 0) {
        int run = 0;
        for (int i = 0; i < NB; ++i) {
            int v = partials[i];
            partials[i] = run;
            run += v;
        }
    }
}

__global__ __launch_bounds__(256) void scan_final_kernel(int* __restrict__ counts_cursor,
                                                         int* __restrict__ row_ptr,
                                                         const int* __restrict__ partials) {
    int b = blockIdx.x, t = threadIdx.x;
    int base = b * SCAN_CHUNK + t * 8;
    int v[8];
    int tsum = 0;
#pragma unroll
    for (int j = 0; j < 8; ++j) {
        int i = base + j;
        v[j] = (i < N_NODES) ? counts_cursor[i] : 0;
        tsum += v[j];
    }
    __shared__ int sd[256];
    sd[t] = tsum;
    __syncthreads();
    for (int off = 1; off < 256; off <<= 1) {
        int x = (t >= off) ? sd[t - off] : 0;
        __syncthreads();
        sd[t] += x;
        __syncthreads();
    }
    int run = sd[t] - tsum + partials[b];
#pragma unroll
    for (int j = 0; j < 8; ++j) {
        int i = base + j;
        if (i < N_NODES) {
            row_ptr[i] = run;
            counts_cursor[i] = run;
        }
        run += v[j];
    }
    if (b == 0 && t == 0) row_ptr[N_NODES] = N_EDGES;
}

// bucket staging cursors: bucket b's staging region == its final pk index range.
__global__ void bucket_init_kernel(const int* __restrict__ row_ptr,
                                   int* __restrict__ bucket_cursor) {
    int t = threadIdx.x;
    if (t < NBUCK2) {
        int node = t << BK2_SHIFT;
        bucket_cursor[t] = row_ptr[node < N_NODES ? node : N_NODES];
    }
}

// Pass A: block-aggregated multi-split into 391 buckets. 1024 thr x 8 edges;
// per-(block,bucket) runs ~21 entries x 8B = 168B (mostly full lines).
// Staged entry: x = src | (local_dst<<17)  (src<2^17, local_dst<256), y = w bits.
__global__ __launch_bounds__(1024) void bin_kernel(const int* __restrict__ esrc,
                                                   const int* __restrict__ edst,
                                                   const float* __restrict__ ew,
                                                   int* __restrict__ bucket_cursor,
                                                   int2* __restrict__ spk) {
    __shared__ int lcount[NBUCK2];
    __shared__ int lbase[NBUCK2];
    int tid = threadIdx.x;
    if (tid < NBUCK2) lcount[tid] = 0;
    __syncthreads();
    int e0 = blockIdx.x * BIN_EPB + tid * 8;
    bool act = (e0 < N_EDGES);
    int dd[8], ss[8], wb[8], bi[8], rank[8];
    if (act) {
        iv4 d0 = __builtin_nontemporal_load((const iv4*)(edst + e0));
        iv4 d1 = __builtin_nontemporal_load((const iv4*)(edst + e0 + 4));
        iv4 s0 = __builtin_nontemporal_load((const iv4*)(esrc + e0));
        iv4 s1 = __builtin_nontemporal_load((const iv4*)(esrc + e0 + 4));
        iv4 w0 = __builtin_nontemporal_load((const iv4*)(ew + e0));
        iv4 w1 = __builtin_nontemporal_load((const iv4*)(ew + e0 + 4));
        dd[0]=d0.x; dd[1]=d0.y; dd[2]=d0.z; dd[3]=d0.w;
        dd[4]=d1.x; dd[5]=d1.y; dd[6]=d1.z; dd[7]=d1.w;
        ss[0]=s0.x; ss[1]=s0.y; ss[2]=s0.z; ss[3]=s0.w;
        ss[4]=s1.x; ss[5]=s1.y; ss[6]=s1.z; ss[7]=s1.w;
        wb[0]=w0.x; wb[1]=w0.y; wb[2]=w0.z; wb[3]=w0.w;
        wb[4]=w1.x; wb[5]=w1.y; wb[6]=w1.z; wb[7]=w1.w;
#pragma unroll
        for (int k = 0; k < 8; ++k) {
            bi[k] = dd[k] >> BK2_SHIFT;
            rank[k] = atomicAdd(&lcount[bi[k]], 1);
        }
    }
    __syncthreads();
    if (tid < NBUCK2) lbase[tid] = atomicAdd(&bucket_cursor[tid], lcount[tid]);
    __syncthreads();
    if (act) {
#pragma unroll
        for (int k = 0; k < 8; ++k) {
            int pos = lbase[bi[k]] + rank[k];
            int ld = dd[k] & 255;
            spk[pos] = make_int2(ss[k] | (ld << 17), wb[k]);
        }
    }
}

// Pass B: one block OWNS one bucket. Contiguous nt reads of the staged run;
// scattered pk writes land ONLY in this block's 64KB region -> L2-merged,
// full-line writebacks.
__global__ __launch_bounds__(512) void scatter_bucket_kernel(const int2* __restrict__ spk,
                                                             const int* __restrict__ row_ptr,
                                                             int* __restrict__ cursor,
                                                             int2* __restrict__ pk) {
    int b = blockIdx.x;
    int nb0 = b << BK2_SHIFT;
    int nb1 = (b + 1) << BK2_SHIFT; if (nb1 > N_NODES) nb1 = N_NODES;
    int start = row_ptr[nb0];
    int end   = row_ptr[nb1];
    int tid = threadIdx.x;
    int e = start + tid;
    // x2 unrolled independent chains for ILP
    for (; e + 512 < end; e += 1024) {
        iv2 s0 = __builtin_nontemporal_load((const iv2*)(spk + e));
        iv2 s1 = __builtin_nontemporal_load((const iv2*)(spk + e + 512));
        int dst0 = nb0 + ((unsigned)s0.x >> 17);
        int dst1 = nb0 + ((unsigned)s1.x >> 17);
        int pos0 = atomicAdd(&cursor[dst0], 1);
        int pos1 = atomicAdd(&cursor[dst1], 1);
        pk[pos0] = make_int2(s0.x & 0x1FFFF, s0.y);
        pk[pos1] = make_int2(s1.x & 0x1FFFF, s1.y);
    }
    if (e < end) {
        iv2 s0 = __builtin_nontemporal_load((const iv2*)(spk + e));
        int dst0 = nb0 + ((unsigned)s0.x >> 17);
        int pos0 = atomicAdd(&cursor[dst0], 1);
        pk[pos0] = make_int2(s0.x & 0x1FFFF, s0.y);
    }
}

// ---------------- small transpose+cast: W[K][N] f32 -> WT[N][K] bf16 ----------------
__global__ __launch_bounds__(256) void transpose_w_kernel(const float* __restrict__ W,
                                                          __hip_bfloat16* __restrict__ WT,
                                                          int K, int N) {
    int idx = blockIdx.x * 256 + threadIdx.x;
    if (idx < K * N) {
        int k = idx / N, n = idx % N;
        WT[(size_t)n * K + k] = __float2bfloat16(W[idx]);
    }
}

// ---------------- GEMM1: support0[M,256](fp8) = A[M,512](f32) @ W1T[256,512]^T -------
// r14 config: 8 waves (512 thr), BM=128 x BN=256 in ONE block, A read exactly once.
__global__ __launch_bounds__(512) void gemm1_mfma(const float* __restrict__ A,
                                                  const __hip_bfloat16* __restrict__ BT,
                                                  unsigned char* __restrict__ C8,
                                                  int M) {
    constexpr int K = NFEAT;   // 512
    constexpr int N = NHID;    // 256
    constexpr int BM = 128, BK = 32;
    constexpr int NSTEP = K / BK;  // 16
    __shared__ __align__(16) float          As[2][BM * BK];  // 2 x 16 KB
    __shared__ __align__(16) __hip_bfloat16 Bs[2][256 * BK]; // 2 x 16 KB
    const int tid = threadIdx.x;
    const int lane = tid & 63, wave = tid >> 6;   // 8 waves
    const int wr = wave >> 2, wc = wave & 3;      // 2 x 4 wave grid
    const int laneRow = lane & 15, laneK = lane >> 4;
    const int row0 = blockIdx.x * BM;

    f32x4 acc[4][4] = {};

    auto STAGE = [&](int step) {
        {
            float* dst = As[step & 1];
#pragma unroll
            for (int it = 0; it < 2; ++it) {
                int q = wave * 2 + it;            // 16 chunks of 1KB
                int r = q * 8 + (lane >> 3);
                int c16 = lane & 7;
                int src_c = (c16 ^ ((r & 3) << 1)) * 4;  // floats
                int rg = row0 + r; rg = (rg < M) ? rg : (M - 1);
                const float* src = A + (size_t)rg * K + step * BK + src_c;
                GLOBAL_TO_LDS(src, dst + q * 256 + lane * 4);
            }
        }
        {
            __hip_bfloat16* dst = Bs[step & 1];
#pragma unroll
            for (int it = 0; it < 2; ++it) {
                int idx2 = tid + it * 512;        // 1024 granules of 16B
                int n = idx2 >> 2;
                int gk = (idx2 & 3) ^ ((n >> 1) & 3);
                const __hip_bfloat16* src = BT + (size_t)n * K + step * BK + gk * 8;
                GLOBAL_TO_LDS(src, dst + (size_t)idx2 * 8);
            }
        }
    };

    STAGE(0);

#pragma unroll
    for (int t = 0; t < NSTEP; ++t) {
        __syncthreads();
        if (t + 1 < NSTEP) STAGE(t + 1);
        short8 af[4];
#pragma unroll
        for (int i = 0; i < 4; ++i) {
            int rr = wr * 64 + i * 16 + laneRow;
            int ck = laneK ^ (rr & 3);
            const float* ap = As[t & 1] + rr * BK + ck * 8;
            fv4 a0 = *(const fv4*)ap;
            fv4 a1 = *(const fv4*)(ap + 4);
            short8 v;
#pragma unroll
            for (int j = 0; j < 4; ++j) v[j] = f2bf_bits(a0[j]);
#pragma unroll
            for (int j = 0; j < 4; ++j) v[4 + j] = f2bf_bits(a1[j]);
            af[i] = v;
        }
        short8 bfr[4];
#pragma unroll
        for (int j = 0; j < 4; ++j) {
            int n = wc * 64 + j * 16 + laneRow;
            int pg = laneK ^ ((n >> 1) & 3);
            bfr[j] = *(const short8*)(Bs[t & 1] + n * BK + pg * 8);
        }
#pragma unroll
        for (int i = 0; i < 4; ++i)
#pragma unroll
            for (int j = 0; j < 4; ++j)
                acc[i][j] = __builtin_amdgcn_mfma_f32_16x16x32_bf16(af[i], bfr[j], acc[i][j], 0, 0, 0);
    }
#pragma unroll
    for (int i = 0; i < 4; ++i) {
        int rbase = row0 + wr * 64 + i * 16 + laneK * 4;
#pragma unroll
        for (int j = 0; j < 4; ++j) {
            int col = wc * 64 + j * 16 + laneRow;
#pragma unroll
            for (int q = 0; q < 4; ++q) {
                int row = rbase + q;
                if (row < M) C8[(size_t)row * N + col] = f2fp8(acc[i][j][q]);
            }
        }
    }
}

// ---------------- GEMM2: support1[M,64](fp8) = H0[M,256](bf16) @ W2T[64,256]^T ------
__global__ __launch_bounds__(256) void gemm2_mfma(const __hip_bfloat16* __restrict__ A,
                                                  const __hip_bfloat16* __restrict__ BT,
                                                  unsigned char* __restrict__ C8,
                                                  int M) {
    constexpr int K = NHID;    // 256
    constexpr int N = NCLASS;  // 64
    constexpr int BM = 128;
    __shared__ __align__(16) __hip_bfloat16 Bs[N * K];  // 32 KB
    const int tid = threadIdx.x;
    const int lane = tid & 63, wave = tid >> 6;
    const int wr = wave >> 1, wc = wave & 1;
    const int laneRow = lane & 15, laneK = lane >> 4;
    const int row0 = blockIdx.x * BM;

#pragma unroll
    for (int it = 0; it < 8; ++it) {
        int idx = tid + it * 256;
        int n = idx >> 5;
        int kk = (idx & 31) ^ (n & 7);
        const __hip_bfloat16* src = BT + (size_t)n * K + kk * 8;
        GLOBAL_TO_LDS(src, Bs + (size_t)idx * 8);
    }

    int arow[4];
#pragma unroll
    for (int i = 0; i < 4; ++i) {
        int r = row0 + wr * 64 + i * 16 + laneRow;
        arow[i] = (r < M) ? r : (M - 1);
    }

    f32x4 acc[4][2] = {};
    __syncthreads();

#pragma unroll
    for (int k0 = 0; k0 < K; k0 += 32) {
        short8 af[4];
#pragma unroll
        for (int i = 0; i < 4; ++i)
            af[i] = *(const short8*)(A + (size_t)arow[i] * K + k0 + laneK * 8);
        short8 bfr[2];
#pragma unroll
        for (int j = 0; j < 2; ++j) {
            int n = wc * 32 + j * 16 + laneRow;
            int kkw = (k0 >> 3) + laneK;
            int pkk = kkw ^ (n & 7);
            bfr[j] = *(const short8*)(Bs + (size_t)n * 32 * 8 + pkk * 8);
        }
#pragma unroll
        for (int i = 0; i < 4; ++i)
#pragma unroll
            for (int j = 0; j < 2; ++j)
                acc[i][j] = __builtin_amdgcn_mfma_f32_16x16x32_bf16(af[i], bfr[j], acc[i][j], 0, 0, 0);
    }

#pragma unroll
    for (int i = 0; i < 4; ++i) {
        int rbase = row0 + wr * 64 + i * 16 + laneK * 4;
#pragma unroll
        for (int j = 0; j < 2; ++j) {
            int col = wc * 32 + j * 16 + laneRow;
#pragma unroll
            for (int q = 0; q < 4; ++q) {
                int row = rbase + q;
                if (row < M) C8[(size_t)row * N + col] = f2fp8(acc[i][j][q]);
            }
        }
    }
}

// ---------------- SPMM layer1: one wave = one node = FULL 256-col row. ---------------
__global__ __launch_bounds__(256) void spmm1_kernel(const unsigned char* __restrict__ s0_8,
                                                    const int* __restrict__ row_ptr,
                                                    const int2* __restrict__ pk,
                                                    const float* __restrict__ b1,
                                                    __hip_bfloat16* __restrict__ H0) {
    int node = blockIdx.x * 4 + (threadIdx.x >> 6);
    int lane = threadIdx.x & 63;
    int j = lane >> 4;                 // edge slot 0..3
    int c = lane & 15;                 // column chunk (16 cols each) -> 256 cols
    int coff = c * 16;
    int beg = row_ptr[node], end = row_ptr[node + 1];
    fv2 acc2[8] = {};
    for (int base = beg; base + j < end; base += 8) {
        int2 pe0 = pk[base + j];
        int i1 = base + 4 + j;
        int2 pe1 = (i1 < end) ? pk[i1] : make_int2(0, 0);
        float w0 = __int_as_float(pe0.y);
        float w1 = __int_as_float(pe1.y);
        iv4 v0 = *(const iv4*)(s0_8 + (size_t)pe0.x * NHID + coff);
        iv4 v1 = *(const iv4*)(s0_8 + (size_t)pe1.x * NHID + coff);
        fp8x16_acc_pk(v0, w0, acc2);
        fp8x16_acc_pk(v1, w1, acc2);
    }
    float accf[16];
#pragma unroll
    for (int k = 0; k < 8; ++k) { accf[2 * k] = acc2[k][0]; accf[2 * k + 1] = acc2[k][1]; }
#pragma unroll
    for (int m = 16; m < 64; m <<= 1)
#pragma unroll
        for (int k = 0; k < 16; ++k) accf[k] += __shfl_xor(accf[k], m);
    if (lane < 16) {
        short8 o0, o1;
#pragma unroll
        for (int k = 0; k < 8; ++k)  o0[k] = f2bf_bits(fmaxf(accf[k] + b1[coff + k], 0.f));
#pragma unroll
        for (int k = 0; k < 8; ++k)  o1[k] = f2bf_bits(fmaxf(accf[8 + k] + b1[coff + 8 + k], 0.f));
        __hip_bfloat16* dst = H0 + (size_t)node * NHID + coff;
        *(short8*)dst = o0;
        *(short8*)(dst + 8) = o1;
    }
}

// ---------------- SPMM layer2 + bias + log_softmax ----------------------------------
__global__ __launch_bounds__(256) void spmm2_softmax_kernel(const unsigned char* __restrict__ s1_8,
                                                            const int* __restrict__ row_ptr,
                                                            const int2* __restrict__ pk,
                                                            const float* __restrict__ b2,
                                                            float* __restrict__ out) {
    int node = blockIdx.x * 4 + (threadIdx.x >> 6);
    int lane = threadIdx.x & 63;
    int j = lane >> 3;   // edge slot 0..7
    int c = lane & 7;    // class chunk (8 classes each)
    int beg = row_ptr[node], end = row_ptr[node + 1];
    fv2 acc2[4] = {};
    for (int base = beg; base + j < end; base += 16) {
        int2 pe0 = pk[base + j];
        int i1 = base + 8 + j;
        int2 pe1 = (i1 < end) ? pk[i1] : make_int2(0, 0);
        float w0 = __int_as_float(pe0.y);
        float w1 = __int_as_float(pe1.y);
        int2 v0 = *(const int2*)(s1_8 + (size_t)pe0.x * NCLASS + c * 8);
        int2 v1 = *(const int2*)(s1_8 + (size_t)pe1.x * NCLASS + c * 8);
        fp8x8_acc_pk(v0.x, v0.y, w0, acc2);
        fp8x8_acc_pk(v1.x, v1.y, w1, acc2);
    }
    float acc[8];
#pragma unroll
    for (int k = 0; k < 4; ++k) { acc[2 * k] = acc2[k][0]; acc[2 * k + 1] = acc2[k][1]; }
#pragma unroll
    for (int m = 8; m < 64; m <<= 1)
#pragma unroll
        for (int k = 0; k < 8; ++k) acc[k] += __shfl_xor(acc[k], m);

    fv4 blo = *(const fv4*)(b2 + c * 8);
    fv4 bhi = *(const fv4*)(b2 + c * 8 + 4);
    float z[8];
#pragma unroll
    for (int k = 0; k < 4; ++k) z[k] = acc[k] + blo[k];
#pragma unroll
    for (int k = 0; k < 4; ++k) z[4 + k] = acc[4 + k] + bhi[k];

    float mx = z[0];
#pragma unroll
    for (int k = 1; k < 8; ++k) mx = fmaxf(mx, z[k]);
#pragma unroll
    for (int m = 1; m < 8; m <<= 1) mx = fmaxf(mx, __shfl_xor(mx, m));
    float s = 0.f;
#pragma unroll
    for (int k = 0; k < 8; ++k) s += __expf(z[k] - mx);
#pragma unroll
    for (int m = 1; m < 8; m <<= 1) s += __shfl_xor(s, m);
    float lg = __logf(s);
    if (lane < 8) {
        f32x4 o0, o1;
#pragma unroll
        for (int k = 0; k < 4; ++k) o0[k] = z[k] - mx - lg;
#pragma unroll
        for (int k = 0; k < 4; ++k) o1[k] = z[4 + k] - mx - lg;
        float* dst = out + (size_t)node * NCLASS + c * 8;
        *(f32x4*)dst = o0;
        *(f32x4*)(dst + 4) = o1;
    }
}

// ---------------- host launch ----------------
extern "C" void kernel_launch(void* const* d_in, const int* in_sizes, int n_in,
                              void* d_out, int out_size, void* d_ws, size_t ws_size,
                              hipStream_t stream) {
    const float* x    = (const float*)d_in[0];
    const int*   esrc = (const int*)d_in[1];
    const int*   edst = (const int*)d_in[2];
    const float* ew   = (const float*)d_in[3];
    const float* W1   = (const float*)d_in[4];
    const float* b1   = (const float*)d_in[5];
    const float* W2   = (const float*)d_in[6];
    const float* b2   = (const float*)d_in[7];
    float* out = (float*)d_out;

    char* ws = (char*)d_ws;
    size_t off = 0;
    auto alloc = [&](size_t bytes) {
        size_t o = off;
        off = (off + bytes + 255) & ~(size_t)255;
        return o;
    };
    unsigned char* support0 = (unsigned char*)(ws + alloc((size_t)N_NODES * NHID));
    __hip_bfloat16* H0      = (__hip_bfloat16*)(ws + alloc((size_t)N_NODES * NHID * 2));
    unsigned char* support1 = (unsigned char*)(ws + alloc((size_t)N_NODES * NCLASS));
    int2*  pk         = (int2*)(ws + alloc((size_t)N_EDGES * 8));
    int2*  spk        = (int2*)(ws + alloc((size_t)N_EDGES * 8));
    int*   row_ptr    = (int*)(ws + alloc((size_t)(N_NODES + 1) * 4));
    int*   cursor     = (int*)(ws + alloc((size_t)N_NODES * 4));
    int*   partials   = (int*)(ws + alloc(256 * 4));
    int*   bucket_cursor = (int*)(ws + alloc(512 * 4));
    __hip_bfloat16* W1T = (__hip_bfloat16*)(ws + alloc((size_t)NHID * NFEAT * 2));
    __hip_bfloat16* W2T = (__hip_bfloat16*)(ws + alloc((size_t)NCLASS * NHID * 2));

    // --- weight transposes (bf16) ---
    transpose_w_kernel<<<(NFEAT * NHID + 255) / 256, 256, 0, stream>>>(W1, W1T, NFEAT, NHID);
    transpose_w_kernel<<<(NHID * NCLASS + 255) / 256, 256, 0, stream>>>(W2, W2T, NHID, NCLASS);

    // --- CSR build: hist -> scan -> bucket bin -> per-bucket scatter ---
    hipMemsetAsync(cursor, 0, (size_t)N_NODES * 4, stream);
    hist_kernel<<<NCHUNK, 256, 0, stream>>>(edst, cursor);
    scan_part_kernel<<<NB, 256, 0, stream>>>(cursor, partials);
    scan_mid_kernel<<<1, 64, 0, stream>>>(partials);
    scan_final_kernel<<<NB, 256, 0, stream>>>(cursor, row_ptr, partials);
    bucket_init_kernel<<<1, 512, 0, stream>>>(row_ptr, bucket_cursor);
    bin_kernel<<<NBIN, 1024, 0, stream>>>(esrc, edst, ew, bucket_cursor, spk);
    scatter_bucket_kernel<<<NBUCK2, 512, 0, stream>>>(spk, row_ptr, cursor, pk);

    // --- Layer 1 ---
    gemm1_mfma<<<(N_NODES + 127) / 128, 512, 0, stream>>>(x, W1T, support0, N_NODES);
    spmm1_kernel<<<N_NODES / 4, 256, 0, stream>>>(support0, row_ptr, pk, b1, H0);

    // --- Layer 2 ---
    gemm2_mfma<<<(N_NODES + 127) / 128, 256, 0, stream>>>(H0, W2T, support1, N_NODES);
    spmm2_softmax_kernel<<<N_NODES / 4, 256, 0, stream>>>(support1, row_ptr, pk, b2, out);
}

// Round 17
// 333.983 us; speedup vs baseline: 1.6554x; 1.5269x over previous
//
#include <hip/hip_runtime.h>
#include <hip/hip_bf16.h>

// ---------------- problem constants (match reference) ----------------
static constexpr int N_NODES = 100000;
static constexpr int N_EDGES = 3200000;
static constexpr int NFEAT   = 512;
static constexpr int NHID    = 256;
static constexpr int NCLASS  = 64;

// bucketed CSR build (r16/r17): 256 nodes per bucket. One finalize block OWNS one
// bucket's pk region -> L2-merged full-line writebacks; LDS atomics everywhere.
static constexpr int BK2_SHIFT = 8;
static constexpr int NBUCK2 = (N_NODES + 255) >> 8;            // 391
static constexpr int BIN_EPB = 8192;                           // 1024 thr * 8
static constexpr int NBIN = (N_EDGES + BIN_EPB - 1) / BIN_EPB; // 391

using short8 = __attribute__((ext_vector_type(8))) short;
using f32x4  = __attribute__((ext_vector_type(4))) float;
using fv4    = __attribute__((ext_vector_type(4))) float;
using fv2    = __attribute__((ext_vector_type(2))) float;
using iv4    = __attribute__((ext_vector_type(4))) int;
using iv2    = __attribute__((ext_vector_type(2))) int;
using fvec4  = __attribute__((ext_vector_type(4))) float;

__device__ __forceinline__ short f2bf_bits(float f) {
    __hip_bfloat16 h = __float2bfloat16(f);
    return *reinterpret_cast<short*>(&h);
}

// fp8 (OCP e4m3) helpers — gfx950 v_cvt_pk_* instructions
__device__ __forceinline__ unsigned char f2fp8(float v) {
    int p = __builtin_amdgcn_cvt_pk_fp8_f32(v, v, 0, false);
    return (unsigned char)(p & 0xff);
}

// acc2[0..3] += w * fp8[0..7] (packed fv2 -> v_pk_fma_f32)
__device__ __forceinline__ void fp8x8_acc_pk(int vx, int vy, float w, fv2* acc2) {
    fv2 w2; w2[0] = w; w2[1] = w;
    acc2[0] += w2 * __builtin_amdgcn_cvt_pk_f32_fp8(vx, false);
    acc2[1] += w2 * __builtin_amdgcn_cvt_pk_f32_fp8(vx, true);
    acc2[2] += w2 * __builtin_amdgcn_cvt_pk_f32_fp8(vy, false);
    acc2[3] += w2 * __builtin_amdgcn_cvt_pk_f32_fp8(vy, true);
}

// acc2[0..7] += w * fp8[0..15] (16 cols from one 16B gather)
__device__ __forceinline__ void fp8x16_acc_pk(iv4 v, float w, fv2* acc2) {
    fp8x8_acc_pk(v.x, v.y, w, acc2);
    fp8x8_acc_pk(v.z, v.w, w, acc2 + 4);
}

#define GLOBAL_TO_LDS(gsrc, ldst)                                                        \
    __builtin_amdgcn_global_load_lds((const __attribute__((address_space(1))) void*)(gsrc), \
                                     (__attribute__((address_space(3))) void*)(ldst), 16, 0, 0)

// ---------------- CSR build (fully bucketed; no 100K-wide global atomics) -----------
// r17: r16's hist did 3.2M random global atomics -> 100 MB atomic writebacks, 130us.
// Replace with per-block LDS bucket histogram: 391 global atomics per block total.
__global__ __launch_bounds__(1024) void bucket_hist_kernel(const int* __restrict__ edst,
                                                           int* __restrict__ bcnt) {
    __shared__ int lcount[NBUCK2];
    int tid = threadIdx.x;
    if (tid < NBUCK2) lcount[tid] = 0;
    __syncthreads();
    int e0 = blockIdx.x * BIN_EPB + tid * 8;
    if (e0 < N_EDGES) {
        iv4 d0 = __builtin_nontemporal_load((const iv4*)(edst + e0));
        iv4 d1 = __builtin_nontemporal_load((const iv4*)(edst + e0 + 4));
        atomicAdd(&lcount[d0.x >> BK2_SHIFT], 1);
        atomicAdd(&lcount[d0.y >> BK2_SHIFT], 1);
        atomicAdd(&lcount[d0.z >> BK2_SHIFT], 1);
        atomicAdd(&lcount[d0.w >> BK2_SHIFT], 1);
        atomicAdd(&lcount[d1.x >> BK2_SHIFT], 1);
        atomicAdd(&lcount[d1.y >> BK2_SHIFT], 1);
        atomicAdd(&lcount[d1.z >> BK2_SHIFT], 1);
        atomicAdd(&lcount[d1.w >> BK2_SHIFT], 1);
    }
    __syncthreads();
    if (tid < NBUCK2) atomicAdd(&bcnt[tid], lcount[tid]);
}

// scan of 391 bucket counts (one block); seeds boffs + bin staging cursors.
__global__ __launch_bounds__(512) void bucket_scan_kernel(const int* __restrict__ bcnt,
                                                          int* __restrict__ boffs,
                                                          int* __restrict__ bucket_cursor,
                                                          int* __restrict__ row_ptr) {
    __shared__ int sd[512];
    int t = threadIdx.x;
    int v = (t < NBUCK2) ? bcnt[t] : 0;
    sd[t] = v;
    __syncthreads();
    for (int off = 1; off < 512; off <<= 1) {
        int x = (t >= off) ? sd[t - off] : 0;
        __syncthreads();
        sd[t] += x;
        __syncthreads();
    }
    int excl = sd[t] - v;
    if (t < NBUCK2) { boffs[t] = excl; bucket_cursor[t] = excl; }
    if (t == 0) { boffs[NBUCK2] = N_EDGES; row_ptr[N_NODES] = N_EDGES; }
}

// Pass A: block-aggregated multi-split into 391 buckets. 1024 thr x 8 edges;
// staged entry: x = src | (local_dst<<17)  (src<2^17, local_dst<256), y = w bits.
__global__ __launch_bounds__(1024) void bin_kernel(const int* __restrict__ esrc,
                                                   const int* __restrict__ edst,
                                                   const float* __restrict__ ew,
                                                   int* __restrict__ bucket_cursor,
                                                   int2* __restrict__ spk) {
    __shared__ int lcount[NBUCK2];
    __shared__ int lbase[NBUCK2];
    int tid = threadIdx.x;
    if (tid < NBUCK2) lcount[tid] = 0;
    __syncthreads();
    int e0 = blockIdx.x * BIN_EPB + tid * 8;
    bool act = (e0 < N_EDGES);
    int dd[8], ss[8], wb[8], bi[8], rank[8];
    if (act) {
        iv4 d0 = __builtin_nontemporal_load((const iv4*)(edst + e0));
        iv4 d1 = __builtin_nontemporal_load((const iv4*)(edst + e0 + 4));
        iv4 s0 = __builtin_nontemporal_load((const iv4*)(esrc + e0));
        iv4 s1 = __builtin_nontemporal_load((const iv4*)(esrc + e0 + 4));
        iv4 w0 = __builtin_nontemporal_load((const iv4*)(ew + e0));
        iv4 w1 = __builtin_nontemporal_load((const iv4*)(ew + e0 + 4));
        dd[0]=d0.x; dd[1]=d0.y; dd[2]=d0.z; dd[3]=d0.w;
        dd[4]=d1.x; dd[5]=d1.y; dd[6]=d1.z; dd[7]=d1.w;
        ss[0]=s0.x; ss[1]=s0.y; ss[2]=s0.z; ss[3]=s0.w;
        ss[4]=s1.x; ss[5]=s1.y; ss[6]=s1.z; ss[7]=s1.w;
        wb[0]=w0.x; wb[1]=w0.y; wb[2]=w0.z; wb[3]=w0.w;
        wb[4]=w1.x; wb[5]=w1.y; wb[6]=w1.z; wb[7]=w1.w;
#pragma unroll
        for (int k = 0; k < 8; ++k) {
            bi[k] = dd[k] >> BK2_SHIFT;
            rank[k] = atomicAdd(&lcount[bi[k]], 1);
        }
    }
    __syncthreads();
    if (tid < NBUCK2) lbase[tid] = atomicAdd(&bucket_cursor[tid], lcount[tid]);
    __syncthreads();
    if (act) {
#pragma unroll
        for (int k = 0; k < 8; ++k) {
            int pos = lbase[bi[k]] + rank[k];
            int ld = dd[k] & 255;
            spk[pos] = make_int2(ss[k] | (ld << 17), wb[k]);
        }
    }
}

// Pass B: one block OWNS one bucket. LDS-histogram its staged run (256 counters),
// LDS scan -> row_ptr for its 256 nodes (coalesced write), then scatter into final
// pk order via LDS cursor atomics. No global atomics, writes confined to the
// bucket's 64KB region -> L2-merged full-line writebacks.
__global__ __launch_bounds__(512) void finalize_bucket_kernel(const int2* __restrict__ spk,
                                                              const int* __restrict__ boffs,
                                                              int* __restrict__ row_ptr,
                                                              int2* __restrict__ pk) {
    int b = blockIdx.x;
    int nb0 = b << BK2_SHIFT;
    int nnode = N_NODES - nb0; if (nnode > 256) nnode = 256;
    int start = boffs[b], end = boffs[b + 1];
    __shared__ int cnt[256];
    __shared__ int pref[256];
    int tid = threadIdx.x;
    if (tid < 256) cnt[tid] = 0;
    __syncthreads();
    // pass 1: count local dsts
    for (int e = start + tid; e < end; e += 512) {
        int ld = ((unsigned)spk[e].x >> 17) & 255;
        atomicAdd(&cnt[ld], 1);
    }
    __syncthreads();
    if (tid < 256) pref[tid] = cnt[tid];
    __syncthreads();
    for (int off = 1; off < 256; off <<= 1) {
        int x = 0;
        if (tid < 256 && tid >= off) x = pref[tid - off];
        __syncthreads();
        if (tid < 256) pref[tid] += x;
        __syncthreads();
    }
    // pref inclusive; exclusive = pref - cnt
    if (tid < 256) {
        int excl = pref[tid] - cnt[tid];
        if (tid < nnode) row_ptr[nb0 + tid] = start + excl;
        cnt[tid] = excl;               // reuse as local cursor
    }
    __syncthreads();
    // pass 2: scatter (staged run is L2-hot from pass 1)
    for (int e = start + tid; e < end; e += 512) {
        int2 s = spk[e];
        int ld = ((unsigned)s.x >> 17) & 255;
        int pos = start + atomicAdd(&cnt[ld], 1);
        pk[pos] = make_int2(s.x & 0x1FFFF, s.y);
    }
}

// ---------------- small transpose+cast: W[K][N] f32 -> WT[N][K] bf16 ----------------
__global__ __launch_bounds__(256) void transpose_w_kernel(const float* __restrict__ W,
                                                          __hip_bfloat16* __restrict__ WT,
                                                          int K, int N) {
    int idx = blockIdx.x * 256 + threadIdx.x;
    if (idx < K * N) {
        int k = idx / N, n = idx % N;
        WT[(size_t)n * K + k] = __float2bfloat16(W[idx]);
    }
}

// ---------------- GEMM1: support0[M,256](fp8) = A[M,512](f32) @ W1T[256,512]^T -------
// r14 config: 8 waves (512 thr), BM=128 x BN=256 in ONE block, A read exactly once.
__global__ __launch_bounds__(512) void gemm1_mfma(const float* __restrict__ A,
                                                  const __hip_bfloat16* __restrict__ BT,
                                                  unsigned char* __restrict__ C8,
                                                  int M) {
    constexpr int K = NFEAT;   // 512
    constexpr int N = NHID;    // 256
    constexpr int BM = 128, BK = 32;
    constexpr int NSTEP = K / BK;  // 16
    __shared__ __align__(16) float          As[2][BM * BK];  // 2 x 16 KB
    __shared__ __align__(16) __hip_bfloat16 Bs[2][256 * BK]; // 2 x 16 KB
    const int tid = threadIdx.x;
    const int lane = tid & 63, wave = tid >> 6;   // 8 waves
    const int wr = wave >> 2, wc = wave & 3;      // 2 x 4 wave grid
    const int laneRow = lane & 15, laneK = lane >> 4;
    const int row0 = blockIdx.x * BM;

    f32x4 acc[4][4] = {};

    auto STAGE = [&](int step) {
        {
            float* dst = As[step & 1];
#pragma unroll
            for (int it = 0; it < 2; ++it) {
                int q = wave * 2 + it;            // 16 chunks of 1KB
                int r = q * 8 + (lane >> 3);
                int c16 = lane & 7;
                int src_c = (c16 ^ ((r & 3) << 1)) * 4;  // floats
                int rg = row0 + r; rg = (rg < M) ? rg : (M - 1);
                const float* src = A + (size_t)rg * K + step * BK + src_c;
                GLOBAL_TO_LDS(src, dst + q * 256 + lane * 4);
            }
        }
        {
            __hip_bfloat16* dst = Bs[step & 1];
#pragma unroll
            for (int it = 0; it < 2; ++it) {
                int idx2 = tid + it * 512;        // 1024 granules of 16B
                int n = idx2 >> 2;
                int gk = (idx2 & 3) ^ ((n >> 1) & 3);
                const __hip_bfloat16* src = BT + (size_t)n * K + step * BK + gk * 8;
                GLOBAL_TO_LDS(src, dst + (size_t)idx2 * 8);
            }
        }
    };

    STAGE(0);

#pragma unroll
    for (int t = 0; t < NSTEP; ++t) {
        __syncthreads();
        if (t + 1 < NSTEP) STAGE(t + 1);
        short8 af[4];
#pragma unroll
        for (int i = 0; i < 4; ++i) {
            int rr = wr * 64 + i * 16 + laneRow;
            int ck = laneK ^ (rr & 3);
            const float* ap = As[t & 1] + rr * BK + ck * 8;
            fv4 a0 = *(const fv4*)ap;
            fv4 a1 = *(const fv4*)(ap + 4);
            short8 v;
#pragma unroll
            for (int j = 0; j < 4; ++j) v[j] = f2bf_bits(a0[j]);
#pragma unroll
            for (int j = 0; j < 4; ++j) v[4 + j] = f2bf_bits(a1[j]);
            af[i] = v;
        }
        short8 bfr[4];
#pragma unroll
        for (int j = 0; j < 4; ++j) {
            int n = wc * 64 + j * 16 + laneRow;
            int pg = laneK ^ ((n >> 1) & 3);
            bfr[j] = *(const short8*)(Bs[t & 1] + n * BK + pg * 8);
        }
#pragma unroll
        for (int i = 0; i < 4; ++i)
#pragma unroll
            for (int j = 0; j < 4; ++j)
                acc[i][j] = __builtin_amdgcn_mfma_f32_16x16x32_bf16(af[i], bfr[j], acc[i][j], 0, 0, 0);
    }
#pragma unroll
    for (int i = 0; i < 4; ++i) {
        int rbase = row0 + wr * 64 + i * 16 + laneK * 4;
#pragma unroll
        for (int j = 0; j < 4; ++j) {
            int col = wc * 64 + j * 16 + laneRow;
#pragma unroll
            for (int q = 0; q < 4; ++q) {
                int row = rbase + q;
                if (row < M) C8[(size_t)row * N + col] = f2fp8(acc[i][j][q]);
            }
        }
    }
}

// ---------------- GEMM2: support1[M,64](fp8) = H0[M,256](bf16) @ W2T[64,256]^T ------
__global__ __launch_bounds__(256) void gemm2_mfma(const __hip_bfloat16* __restrict__ A,
                                                  const __hip_bfloat16* __restrict__ BT,
                                                  unsigned char* __restrict__ C8,
                                                  int M) {
    constexpr int K = NHID;    // 256
    constexpr int N = NCLASS;  // 64
    constexpr int BM = 128;
    __shared__ __align__(16) __hip_bfloat16 Bs[N * K];  // 32 KB
    const int tid = threadIdx.x;
    const int lane = tid & 63, wave = tid >> 6;
    const int wr = wave >> 1, wc = wave & 1;
    const int laneRow = lane & 15, laneK = lane >> 4;
    const int row0 = blockIdx.x * BM;

#pragma unroll
    for (int it = 0; it < 8; ++it) {
        int idx = tid + it * 256;
        int n = idx >> 5;
        int kk = (idx & 31) ^ (n & 7);
        const __hip_bfloat16* src = BT + (size_t)n * K + kk * 8;
        GLOBAL_TO_LDS(src, Bs + (size_t)idx * 8);
    }

    int arow[4];
#pragma unroll
    for (int i = 0; i < 4; ++i) {
        int r = row0 + wr * 64 + i * 16 + laneRow;
        arow[i] = (r < M) ? r : (M - 1);
    }

    f32x4 acc[4][2] = {};
    __syncthreads();

#pragma unroll
    for (int k0 = 0; k0 < K; k0 += 32) {
        short8 af[4];
#pragma unroll
        for (int i = 0; i < 4; ++i)
            af[i] = *(const short8*)(A + (size_t)arow[i] * K + k0 + laneK * 8);
        short8 bfr[2];
#pragma unroll
        for (int j = 0; j < 2; ++j) {
            int n = wc * 32 + j * 16 + laneRow;
            int kkw = (k0 >> 3) + laneK;
            int pkk = kkw ^ (n & 7);
            bfr[j] = *(const short8*)(Bs + (size_t)n * 32 * 8 + pkk * 8);
        }
#pragma unroll
        for (int i = 0; i < 4; ++i)
#pragma unroll
            for (int j = 0; j < 2; ++j)
                acc[i][j] = __builtin_amdgcn_mfma_f32_16x16x32_bf16(af[i], bfr[j], acc[i][j], 0, 0, 0);
    }

#pragma unroll
    for (int i = 0; i < 4; ++i) {
        int rbase = row0 + wr * 64 + i * 16 + laneK * 4;
#pragma unroll
        for (int j = 0; j < 2; ++j) {
            int col = wc * 32 + j * 16 + laneRow;
#pragma unroll
            for (int q = 0; q < 4; ++q) {
                int row = rbase + q;
                if (row < M) C8[(size_t)row * N + col] = f2fp8(acc[i][j][q]);
            }
        }
    }
}

// ---------------- SPMM layer1: one wave = one node = FULL 256-col row. ---------------
__global__ __launch_bounds__(256) void spmm1_kernel(const unsigned char* __restrict__ s0_8,
                                                    const int* __restrict__ row_ptr,
                                                    const int2* __restrict__ pk,
                                                    const float* __restrict__ b1,
                                                    __hip_bfloat16* __restrict__ H0) {
    int node = blockIdx.x * 4 + (threadIdx.x >> 6);
    int lane = threadIdx.x & 63;
    int j = lane >> 4;                 // edge slot 0..3
    int c = lane & 15;                 // column chunk (16 cols each) -> 256 cols
    int coff = c * 16;
    int beg = row_ptr[node], end = row_ptr[node + 1];
    fv2 acc2[8] = {};
    for (int base = beg; base + j < end; base += 8) {
        int2 pe0 = pk[base + j];
        int i1 = base + 4 + j;
        int2 pe1 = (i1 < end) ? pk[i1] : make_int2(0, 0);
        float w0 = __int_as_float(pe0.y);
        float w1 = __int_as_float(pe1.y);
        iv4 v0 = *(const iv4*)(s0_8 + (size_t)pe0.x * NHID + coff);
        iv4 v1 = *(const iv4*)(s0_8 + (size_t)pe1.x * NHID + coff);
        fp8x16_acc_pk(v0, w0, acc2);
        fp8x16_acc_pk(v1, w1, acc2);
    }
    float accf[16];
#pragma unroll
    for (int k = 0; k < 8; ++k) { accf[2 * k] = acc2[k][0]; accf[2 * k + 1] = acc2[k][1]; }
#pragma unroll
    for (int m = 16; m < 64; m <<= 1)
#pragma unroll
        for (int k = 0; k < 16; ++k) accf[k] += __shfl_xor(accf[k], m);
    if (lane < 16) {
        short8 o0, o1;
#pragma unroll
        for (int k = 0; k < 8; ++k)  o0[k] = f2bf_bits(fmaxf(accf[k] + b1[coff + k], 0.f));
#pragma unroll
        for (int k = 0; k < 8; ++k)  o1[k] = f2bf_bits(fmaxf(accf[8 + k] + b1[coff + 8 + k], 0.f));
        __hip_bfloat16* dst = H0 + (size_t)node * NHID + coff;
        *(short8*)dst = o0;
        *(short8*)(dst + 8) = o1;
    }
}

// ---------------- SPMM layer2 + bias + log_softmax ----------------------------------
__global__ __launch_bounds__(256) void spmm2_softmax_kernel(const unsigned char* __restrict__ s1_8,
                                                            const int* __restrict__ row_ptr,
                                                            const int2* __restrict__ pk,
                                                            const float* __restrict__ b2,
                                                            float* __restrict__ out) {
    int node = blockIdx.x * 4 + (threadIdx.x >> 6);
    int lane = threadIdx.x & 63;
    int j = lane >> 3;   // edge slot 0..7
    int c = lane & 7;    // class chunk (8 classes each)
    int beg = row_ptr[node], end = row_ptr[node + 1];
    fv2 acc2[4] = {};
    for (int base = beg; base + j < end; base += 16) {
        int2 pe0 = pk[base + j];
        int i1 = base + 8 + j;
        int2 pe1 = (i1 < end) ? pk[i1] : make_int2(0, 0);
        float w0 = __int_as_float(pe0.y);
        float w1 = __int_as_float(pe1.y);
        int2 v0 = *(const int2*)(s1_8 + (size_t)pe0.x * NCLASS + c * 8);
        int2 v1 = *(const int2*)(s1_8 + (size_t)pe1.x * NCLASS + c * 8);
        fp8x8_acc_pk(v0.x, v0.y, w0, acc2);
        fp8x8_acc_pk(v1.x, v1.y, w1, acc2);
    }
    float acc[8];
#pragma unroll
    for (int k = 0; k < 4; ++k) { acc[2 * k] = acc2[k][0]; acc[2 * k + 1] = acc2[k][1]; }
#pragma unroll
    for (int m = 8; m < 64; m <<= 1)
#pragma unroll
        for (int k = 0; k < 8; ++k) acc[k] += __shfl_xor(acc[k], m);

    fv4 blo = *(const fv4*)(b2 + c * 8);
    fv4 bhi = *(const fv4*)(b2 + c * 8 + 4);
    float z[8];
#pragma unroll
    for (int k = 0; k < 4; ++k) z[k] = acc[k] + blo[k];
#pragma unroll
    for (int k = 0; k < 4; ++k) z[4 + k] = acc[4 + k] + bhi[k];

    float mx = z[0];
#pragma unroll
    for (int k = 1; k < 8; ++k) mx = fmaxf(mx, z[k]);
#pragma unroll
    for (int m = 1; m < 8; m <<= 1) mx = fmaxf(mx, __shfl_xor(mx, m));
    float s = 0.f;
#pragma unroll
    for (int k = 0; k < 8; ++k) s += __expf(z[k] - mx);
#pragma unroll
    for (int m = 1; m < 8; m <<= 1) s += __shfl_xor(s, m);
    float lg = __logf(s);
    if (lane < 8) {
        f32x4 o0, o1;
#pragma unroll
        for (int k = 0; k < 4; ++k) o0[k] = z[k] - mx - lg;
#pragma unroll
        for (int k = 0; k < 4; ++k) o1[k] = z[4 + k] - mx - lg;
        float* dst = out + (size_t)node * NCLASS + c * 8;
        *(f32x4*)dst = o0;
        *(f32x4*)(dst + 4) = o1;
    }
}

// ---------------- host launch ----------------
extern "C" void kernel_launch(void* const* d_in, const int* in_sizes, int n_in,
                              void* d_out, int out_size, void* d_ws, size_t ws_size,
                              hipStream_t stream) {
    const float* x    = (const float*)d_in[0];
    const int*   esrc = (const int*)d_in[1];
    const int*   edst = (const int*)d_in[2];
    const float* ew   = (const float*)d_in[3];
    const float* W1   = (const float*)d_in[4];
    const float* b1   = (const float*)d_in[5];
    const float* W2   = (const float*)d_in[6];
    const float* b2   = (const float*)d_in[7];
    float* out = (float*)d_out;

    char* ws = (char*)d_ws;
    size_t off = 0;
    auto alloc = [&](size_t bytes) {
        size_t o = off;
        off = (off + bytes + 255) & ~(size_t)255;
        return o;
    };
    unsigned char* support0 = (unsigned char*)(ws + alloc((size_t)N_NODES * NHID));
    __hip_bfloat16* H0      = (__hip_bfloat16*)(ws + alloc((size_t)N_NODES * NHID * 2));
    unsigned char* support1 = (unsigned char*)(ws + alloc((size_t)N_NODES * NCLASS));
    int2*  pk         = (int2*)(ws + alloc((size_t)N_EDGES * 8));
    int2*  spk        = (int2*)(ws + alloc((size_t)N_EDGES * 8));
    int*   row_ptr    = (int*)(ws + alloc((size_t)(N_NODES + 1) * 4));
    int*   bcnt       = (int*)(ws + alloc(512 * 4));
    int*   boffs      = (int*)(ws + alloc(512 * 4));
    int*   bucket_cursor = (int*)(ws + alloc(512 * 4));
    __hip_bfloat16* W1T = (__hip_bfloat16*)(ws + alloc((size_t)NHID * NFEAT * 2));
    __hip_bfloat16* W2T = (__hip_bfloat16*)(ws + alloc((size_t)NCLASS * NHID * 2));

    // --- weight transposes (bf16) ---
    transpose_w_kernel<<<(NFEAT * NHID + 255) / 256, 256, 0, stream>>>(W1, W1T, NFEAT, NHID);
    transpose_w_kernel<<<(NHID * NCLASS + 255) / 256, 256, 0, stream>>>(W2, W2T, NHID, NCLASS);

    // --- bucketed CSR build: bucket-hist -> bucket-scan -> bin -> per-bucket finalize ---
    hipMemsetAsync(bcnt, 0, 512 * 4, stream);
    bucket_hist_kernel<<<NBIN, 1024, 0, stream>>>(edst, bcnt);
    bucket_scan_kernel<<<1, 512, 0, stream>>>(bcnt, boffs, bucket_cursor, row_ptr);
    bin_kernel<<<NBIN, 1024, 0, stream>>>(esrc, edst, ew, bucket_cursor, spk);
    finalize_bucket_kernel<<<NBUCK2, 512, 0, stream>>>(spk, boffs, row_ptr, pk);

    // --- Layer 1 ---
    gemm1_mfma<<<(N_NODES + 127) / 128, 512, 0, stream>>>(x, W1T, support0, N_NODES);
    spmm1_kernel<<<N_NODES / 4, 256, 0, stream>>>(support0, row_ptr, pk, b1, H0);

    // --- Layer 2 ---
    gemm2_mfma<<<(N_NODES + 127) / 128, 256, 0, stream>>>(H0, W2T, support1, N_NODES);
    spmm2_softmax_kernel<<<N_NODES / 4, 256, 0, stream>>>(support1, row_ptr, pk, b2, out);
}